// Round 3
// baseline (113.943 us; speedup 1.0000x reference)
//
#include <hip/hip_runtime.h>

#define NBODY 299  // prologue computes t^(1); 299 body iters -> t^(300)

// readlane broadcast: uniform compile-time lane index -> v_readlane_b32 (SGPR)
__device__ __forceinline__ float rdl(float v, int srclane) {
  return __int_as_float(__builtin_amdgcn_readlane(__float_as_int(v), srclane));
}

// quad sum via DPP quad_perm (VALU pipe, no LDS): [1,0,3,2]=0xB1, [2,3,0,1]=0x4E
__device__ __forceinline__ float qsum4(float v) {
  v += __int_as_float(__builtin_amdgcn_update_dpp(0, __float_as_int(v), 0xB1, 0xF, 0xF, false));
  v += __int_as_float(__builtin_amdgcn_update_dpp(0, __float_as_int(v), 0x4E, 0xF, 0xF, false));
  return v;
}

// ---------------------------------------------------------------------------
// Fused kernel: one block (128 threads = 2 waves) per batch element.
// Wave 0 runs the x-coordinate recurrence, wave 1 the y-coordinate.
// Phase 1 (both waves): f64 precompute of C^-1 and the fused iteration
// matrices G (16x10), H (16x6), rowsum(G) — redundant per block (~1-2 us,
// fully parallel) instead of a serial precomp dispatch.
// Phase 2: ADMM recurrence. Per coord, per lane l (obs lanes o=4i+j hold
// trajectory point i / obstacle j; lanes 40..45 hold eq-residual rows):
//   w  = t - obs ;  r2 = wx^2 + wy^2 (partner's w^2 via LDS exchange)
//   u  = max(1, 1/sqrt(r2)) * w ;  cu_k = quadsum(u)
//   A  = s - gtc + sum_k G[k]*4*t_k + sum_e H[e]*t_e
//   n  = sum_k G[k]*cu_k ;  s' = A - n ;  t' = s' - n
// All broadcasts are intra-wave readlanes; the ONLY cross-wave traffic is
// the one-float w^2 exchange (double-buffered by parity; 1 barrier/iter).
// ---------------------------------------------------------------------------
__global__ __launch_bounds__(128) void admm_kernel(
    const float* __restrict__ x, const float* __restrict__ b,
    const float* __restrict__ W1, const float* __restrict__ b1,
    const float* __restrict__ W2, const float* __restrict__ b2,
    const float* __restrict__ P, const float* __restrict__ Pdot,
    const float* __restrict__ Pddot, float* __restrict__ out) {
  __shared__ double M[11][22];
  __shared__ double Aq[6][11];
  __shared__ double Pd[10][11];
  __shared__ double QR[16][11];
  __shared__ float GH[16][17];      // [blk][0..9]=G row, [10..15]=H row, [16]=rowsum(G)
  __shared__ float xch[2][2][64];   // [parity][wave][lane] w^2 exchange

  const int t = threadIdx.x;
  const int w = t >> 6;       // 0 = x-coord wave, 1 = y-coord wave
  const int lane = t & 63;
  const int bi = blockIdx.x;

  // ======== Phase 1: per-block f64 precompute ========
  if (t < 110) Pd[t / 11][t % 11] = (double)P[t];
  if (t < 66) {
    int e = t / 11, m = t % 11;
    const float* src = (e % 3 == 0) ? P : ((e % 3 == 1) ? Pdot : Pddot);
    int row = (e < 3) ? 0 : 9;
    Aq[e][m] = (double)src[row * 11 + m];
  }
  __syncthreads();

  if (t < 121) {
    int a = t / 11, c2 = t % 11;
    double c = 0.0;
    for (int i = 0; i < 10; i++) c += 10.0 * (double)Pddot[i * 11 + a] * (double)Pddot[i * 11 + c2];
    for (int i = 0; i < 10; i++) c += 4.8 * Pd[i][a] * Pd[i][c2];
    for (int e = 0; e < 6; e++)  c += 10.0 * Aq[e][a] * Aq[e][c2];
    M[a][c2] = c;
    M[a][11 + c2] = (a == c2) ? 1.0 : 0.0;
  }
  __syncthreads();

  for (int p = 0; p < 11; p++) {
    if (t == p) {
      double inv = 1.0 / M[p][p];
      for (int c = 0; c < 22; c++) M[p][c] *= inv;
    }
    __syncthreads();
    if (t < 11 && t != p) {
      double f = M[t][p];
      for (int c = 0; c < 22; c++) M[t][c] -= f * M[p][c];
    }
    __syncthreads();
  }

  for (int i = t; i < 176; i += 128) {
    int blk = i / 11, m = i % 11;
    double q = 0.0;
    if (blk < 10) { for (int k = 0; k < 11; k++) q += Pd[blk][k] * M[k][11 + m]; }
    else          { for (int k = 0; k < 11; k++) q += Aq[blk - 10][k] * M[k][11 + m]; }
    QR[blk][m] = -q;
  }
  __syncthreads();

  for (int i = t; i < 256; i += 128) {
    int blk = i >> 4, c = i & 15;
    double v = 0.0;
    if (c < 10) {
      for (int m = 0; m < 11; m++) v += QR[blk][m] * Pd[c][m];
      v *= 1.2;
    } else {
      int e = c - 10;
      for (int m = 0; m < 11; m++) v += QR[blk][m] * Aq[e][m];
      v *= 10.0;
    }
    GH[blk][c] = (float)v;
  }
  if (t < 16) {
    double v = 0.0;
    for (int m = 0; m < 11; m++) {
      double cs = 0.0;
      for (int k = 0; k < 10; k++) cs += Pd[k][m];
      v += QR[t][m] * cs;
    }
    GH[t][16] = (float)(1.2 * v);
  }
  __syncthreads();

  // ======== Phase 2: ADMM (wave w handles coordinate w) ========

  // MLP: only b_pred[3] (x) / b_pred[9] (y) survive the mask
  float a1 = b1[lane];
  {
    const float* xr = x + bi * 16;
    const float* w1r = W1 + lane * 16;
    #pragma unroll
    for (int k = 0; k < 16; k++) a1 = fmaf(xr[k], w1r[k], a1);
  }
  float hh = fmaxf(a1, 0.0f);
  float vv = hh * W2[(w ? 9 : 3) * 64 + lane];
  #pragma unroll
  for (int dd = 32; dd >= 1; dd >>= 1) vv += __shfl_xor(vv, dd);
  const float bp = vv + b2[w ? 9 : 3];

  // per-lane constant rows
  const int blk = (lane < 40) ? (lane >> 2) : ((lane < 46) ? (10 + lane - 40) : -1);
  float g[10], h[6], G1 = 0.0f;
  if (blk >= 0) {
    #pragma unroll
    for (int k = 0; k < 10; k++) g[k] = GH[blk][k];
    #pragma unroll
    for (int e = 0; e < 6; e++) h[e] = GH[blk][10 + e];
    G1 = GH[blk][16];
  } else {
    #pragma unroll
    for (int k = 0; k < 10; k++) g[k] = 0.0f;
    #pragma unroll
    for (int e = 0; e < 6; e++) h[e] = 0.0f;
  }

  // b element on req lanes (index 3 from MLP)
  float bown = 0.0f;
  if (lane >= 40 && lane < 46) {
    int e = lane - 40;
    bown = (e == 3) ? bp : b[bi * 12 + (w ? 6 : 0) + e];
  }

  const float gtc = (w == 0 ? 130.79f : 69.2f) * G1;  // SumObs * rowsum(G)

  // s0 = -gtc - H*b ; req lanes additionally -b_own
  float s = -gtc;
  #pragma unroll
  for (int e = 0; e < 6; e++) s = fmaf(-h[e], rdl(bown, 40 + e), s);
  if (lane >= 40 && lane < 46) s -= bown;

  // t^(1): cu0 = 4 for x (u=(1,0)), 0 for y
  float tv = (w == 0) ? fmaf(-4.0f, G1, s) : s;

  const int j = lane & 3;
  const float obsc = (w == 0)
      ? ((j == 0) ? -10.0f : (j == 1) ? 100.79f : (j == 2) ? 30.0f : 10.0f)
      : ((j == 0) ? -10.0f : (j == 1) ? 100.0f  : (j == 2) ? -30.8f : 10.0f);
  const float uzero = (w == 0) ? 1.0f : 0.0f;  // alpha=0,d=1 -> (ca,sa)=(1,0)

  for (int it = 0; it < NBODY; ++it) {
    const int par = it & 1;
    float wv = tv - obsc;
    float w2 = wv * wv;
    xch[par][w][lane] = w2;
    __syncthreads();
    float r2 = w2 + xch[par][1 - w][lane];
    float sc = fmaxf(1.0f, __builtin_amdgcn_rsqf(r2));
    float u = (r2 > 0.0f) ? sc * wv : uzero;
    float cu = qsum4(u);
    float t4 = 4.0f * tv;

    // A = s - gtc + G.(4t) + H.t_req   (2-way split chains)
    float Aa = s - gtc, Ab = 0.0f;
    #pragma unroll
    for (int k = 0; k < 10; k += 2) {
      Aa = fmaf(g[k],     rdl(t4, 4 * k),       Aa);
      Ab = fmaf(g[k + 1], rdl(t4, 4 * (k + 1)), Ab);
    }
    #pragma unroll
    for (int e = 0; e < 6; e += 2) {
      Aa = fmaf(h[e],     rdl(tv, 40 + e), Aa);
      Ab = fmaf(h[e + 1], rdl(tv, 41 + e), Ab);
    }

    // n = G.cu
    float na = 0.0f, nb = 0.0f;
    #pragma unroll
    for (int k = 0; k < 10; k += 2) {
      na = fmaf(g[k],     rdl(cu, 4 * k),       na);
      nb = fmaf(g[k + 1], rdl(cu, 4 * (k + 1)), nb);
    }

    float A = Aa + Ab;
    float n = na + nb;
    s = A - n;
    tv = s - n;
  }

  if (lane < 40 && (lane & 3) == 0) {
    out[bi * 20 + (w ? 10 : 0) + (lane >> 2)] = tv;
  }
}

extern "C" void kernel_launch(void* const* d_in, const int* in_sizes, int n_in,
                              void* d_out, int out_size, void* d_ws, size_t ws_size,
                              hipStream_t stream) {
  const float* x     = (const float*)d_in[0];
  const float* b     = (const float*)d_in[1];
  const float* W1    = (const float*)d_in[2];
  const float* b1    = (const float*)d_in[3];
  const float* W2    = (const float*)d_in[4];
  const float* b2    = (const float*)d_in[5];
  const float* P     = (const float*)d_in[6];
  const float* Pdot  = (const float*)d_in[7];
  const float* Pddot = (const float*)d_in[8];
  float* out = (float*)d_out;

  const int B = in_sizes[0] / 16;  // 512

  admm_kernel<<<B, 128, 0, stream>>>(x, b, W1, b1, W2, b2, P, Pdot, Pddot, out);
}

// Round 5
// 87.929 us; speedup vs baseline: 1.2958x; 1.2958x over previous
//
#include <hip/hip_runtime.h>

#define NBODY 299  // prologue computes tau^(1); 299 body iters -> tau^(300)

// Broadcast within each 16-lane group: all lanes of a group read the group's
// lane k. BitMode: src = ((lane & 0x10) | k)  (per 32-lane half, bit4 kept).
#define BCAST(v, k) __int_as_float(__builtin_amdgcn_ds_swizzle(__float_as_int(v), (((k) << 5) | 0x10)))
// Swap the two 16-groups inside each 32-half: lane ^= 16  (x <-> y coord).
#define XOR16(v) __int_as_float(__builtin_amdgcn_ds_swizzle(__float_as_int(v), 0x401F))

// ---------------------------------------------------------------------------
// One wave (64 lanes) = 2 batch problems x 2 coords x 16 rows.
// lane = 16*q + r;  q = (problem<<1)|coord;  r = row (0..9 traj, 10..15 req).
//
// Exact recurrence (unrolled from the verified round-2 s/t form):
//   t^(k+1) = t^(k) + 4G t - SumObs*G*1 - 2G cu^(k) + G cu^(k-1) + H (treq - b)
// In tau/W form with W = [-G | -H] (as precomputed):
//   tau' = tau + W @ zeta
//     zeta_c (c<10)  = -4*tau_c + 2*cu_c - cu_prev_c + SumObs
//     zeta_c (c=10+e)= -tau_c + b_e          (tau_req == treq)
//   cu_k = sum_j u_kj,  u = max(1, rsqrt(wx^2+wy^2)) * w,  w = t_k - obs_j
//   cu_prev^(0) = 4 (x) / 0 (y).
// Init: tau^(1) = (SumObs + 4*is_x)*rowsum(W_traj) + W_req @ b.
// ---------------------------------------------------------------------------
__global__ __launch_bounds__(64) void admm_kernel(
    const float* __restrict__ x, const float* __restrict__ b,
    const float* __restrict__ W1m, const float* __restrict__ b1,
    const float* __restrict__ W2m, const float* __restrict__ b2,
    const float* __restrict__ P, const float* __restrict__ Pdot,
    const float* __restrict__ Pddot, float* __restrict__ out) {
  __shared__ double Pd[10][11];
  __shared__ double Aq[6][11];
  __shared__ double M[11][22];
  __shared__ double U[16][11];
  __shared__ double colp[11];
  __shared__ float Wl[16][16];
  __shared__ float W1l[16];

  const int t = threadIdx.x;
  const int bid = blockIdx.x;

  // ======== Phase 1: per-block f64 precompute of W, rowsum(Gamma) ========
  for (int i = t; i < 110; i += 64) Pd[i / 11][i % 11] = (double)P[i];
  for (int i = t; i < 66; i += 64) {
    int e = i / 11, m = i % 11;
    const float* src = (e % 3 == 0) ? P : ((e % 3 == 1) ? Pdot : Pddot);
    Aq[e][m] = (double)src[(e < 3 ? 0 : 9) * 11 + m];
  }
  __syncthreads();

  for (int i = t; i < 121; i += 64) {
    int a = i / 11, c = i % 11;
    double acc = 0.0;
    for (int k = 0; k < 10; k++) acc += 10.0 * (double)Pddot[k * 11 + a] * (double)Pddot[k * 11 + c];
    for (int k = 0; k < 10; k++) acc += 4.8 * Pd[k][a] * Pd[k][c];
    for (int e = 0; e < 6; e++)  acc += 10.0 * Aq[e][a] * Aq[e][c];
    M[a][c] = acc;
    M[a][11 + c] = (a == c) ? 1.0 : 0.0;
  }
  __syncthreads();

  for (int p = 0; p < 11; p++) {
    double pv = M[p][p];
    __syncthreads();
    if (t < 22) M[p][t] *= (1.0 / pv);
    __syncthreads();
    if (t < 11) colp[t] = M[t][p];
    __syncthreads();
    for (int i = t; i < 242; i += 64) {
      int r = i / 22, c = i % 22;
      if (r != p) M[r][c] -= colp[r] * M[p][c];
    }
    __syncthreads();
  }

  for (int i = t; i < 176; i += 64) {
    int r = i / 11, m = i % 11;
    double acc = 0.0;
    for (int k = 0; k < 11; k++) acc += ((r < 10) ? Pd[r][k] : Aq[r - 10][k]) * M[k][11 + m];
    U[r][m] = acc;
  }
  __syncthreads();

  for (int i = t; i < 256; i += 64) {
    int r = i >> 4, c = i & 15;
    double acc = 0.0;
    if (c < 10) {
      for (int m = 0; m < 11; m++) acc += U[r][m] * Pd[c][m];
      acc *= 1.2;
    } else {
      for (int m = 0; m < 11; m++) acc += U[r][m] * Aq[c - 10][m];
      acc *= 10.0;
    }
    Wl[r][c] = (float)acc;
  }
  if (t < 16) {
    double acc = 0.0;
    for (int c = 0; c < 10; c++) {
      double d2 = 0.0;
      for (int m = 0; m < 11; m++) d2 += U[t][m] * Pd[c][m];
      acc += d2;
    }
    W1l[t] = (float)(1.2 * acc);
  }
  __syncthreads();

  // ======== Phase 2: MLP (b_pred[3], b_pred[9] for both problems) ========
  float w1r[16];
  #pragma unroll
  for (int k = 0; k < 16; k++) w1r[k] = W1m[t * 16 + k];

  float bp3_0, bp9_0, bp3_1, bp9_1;
  {
    const float* xr = x + (bid * 2 + 0) * 16;
    float a1 = b1[t];
    #pragma unroll
    for (int k = 0; k < 16; k++) a1 = fmaf(xr[k], w1r[k], a1);
    float hh = fmaxf(a1, 0.0f);
    float v3 = hh * W2m[3 * 64 + t];
    float v9 = hh * W2m[9 * 64 + t];
    #pragma unroll
    for (int dd = 32; dd >= 1; dd >>= 1) { v3 += __shfl_xor(v3, dd); v9 += __shfl_xor(v9, dd); }
    bp3_0 = v3 + b2[3];
    bp9_0 = v9 + b2[9];
  }
  {
    const float* xr = x + (bid * 2 + 1) * 16;
    float a1 = b1[t];
    #pragma unroll
    for (int k = 0; k < 16; k++) a1 = fmaf(xr[k], w1r[k], a1);
    float hh = fmaxf(a1, 0.0f);
    float v3 = hh * W2m[3 * 64 + t];
    float v9 = hh * W2m[9 * 64 + t];
    #pragma unroll
    for (int dd = 32; dd >= 1; dd >>= 1) { v3 += __shfl_xor(v3, dd); v9 += __shfl_xor(v9, dd); }
    bp3_1 = v3 + b2[3];
    bp9_1 = v9 + b2[9];
  }

  // ======== Phase 3: lane setup ========
  const int q = t >> 4, r = t & 15;
  const int pidx = q >> 1, c = q & 1;
  const int gbi = bid * 2 + pidx;

  float Wr[16];
  #pragma unroll
  for (int k = 0; k < 16; k++) Wr[k] = Wl[r][k];
  const float W1r = W1l[r];

  const bool isT = (r < 10);
  const float aC = isT ? -4.0f : -1.0f;
  const float m2 = isT ? 2.0f : 0.0f;
  const float mp = isT ? 1.0f : 0.0f;

  float bown = 0.0f;
  if (!isT) {
    int e = r - 10;
    float mlpv = (c == 0) ? (pidx ? bp3_1 : bp3_0) : (pidx ? bp9_1 : bp9_0);
    bown = (e == 3) ? mlpv : b[gbi * 12 + c * 6 + e];
  }
  const float dC = isT ? (c == 0 ? 130.79f : 69.2f) : bown;

  // obstacle constants (own coord / other coord), selected per c once
  const float own0 = -10.0f;
  const float own1 = (c == 0) ? 100.79f : 100.0f;
  const float own2 = (c == 0) ? 30.0f : -30.8f;
  const float own3 = 10.0f;
  const float oth0 = -10.0f;
  const float oth1 = (c == 0) ? 100.0f : 100.79f;
  const float oth2 = (c == 0) ? -30.8f : 30.0f;
  const float oth3 = 10.0f;
  const float uz = (c == 0) ? 1.0f : 0.0f;  // atan2(0,0)=0 -> (ca,sa)=(1,0)

  // ======== Phase 4: init tau^(1), cu_prev^(0) ========
  float tau = (c == 0 ? 134.79f : 69.2f) * W1r;
  tau = fmaf(Wr[10], BCAST(bown, 10), tau);
  tau = fmaf(Wr[11], BCAST(bown, 11), tau);
  tau = fmaf(Wr[12], BCAST(bown, 12), tau);
  tau = fmaf(Wr[13], BCAST(bown, 13), tau);
  tau = fmaf(Wr[14], BCAST(bown, 14), tau);
  tau = fmaf(Wr[15], BCAST(bown, 15), tau);

  float cup = 4.0f * uz * mp;  // cu^(0): 4 for x-traj, 0 otherwise

  // ======== Phase 5: main loop ========
  #define PROJ_ACC(OWN, OTH)                                        \
    {                                                               \
      float wo = tau - (OWN), wt = to - (OTH);                      \
      float r2 = fmaf(wo, wo, wt * wt);                             \
      float sc = fmaxf(1.0f, __builtin_amdgcn_rsqf(r2));            \
      cu += (r2 > 0.0f) ? sc * wo : uz;                             \
    }
  #define DOT_STEP(K, ACC) ACC = fmaf(Wr[K], BCAST(zeta, K), ACC);

  for (int it = 0; it < NBODY; ++it) {
    float to = XOR16(tau);
    float cu;
    {
      float wo = tau - own0, wt = to - oth0;
      float r2 = fmaf(wo, wo, wt * wt);
      float sc = fmaxf(1.0f, __builtin_amdgcn_rsqf(r2));
      cu = (r2 > 0.0f) ? sc * wo : uz;
    }
    PROJ_ACC(own1, oth1)
    PROJ_ACC(own2, oth2)
    PROJ_ACC(own3, oth3)

    // zeta = aC*tau + m2*cu + dC - cu_prev   (cu_prev: one-iteration memory)
    float zeta = fmaf(aC, tau, fmaf(m2, cu, dC) - cup);
    cup = mp * cu;

    float accE = tau, accO = 0.0f;
    DOT_STEP(0, accE)  DOT_STEP(1, accO)
    DOT_STEP(2, accE)  DOT_STEP(3, accO)
    DOT_STEP(4, accE)  DOT_STEP(5, accO)
    DOT_STEP(6, accE)  DOT_STEP(7, accO)
    DOT_STEP(8, accE)  DOT_STEP(9, accO)
    DOT_STEP(10, accE) DOT_STEP(11, accO)
    DOT_STEP(12, accE) DOT_STEP(13, accO)
    DOT_STEP(14, accE) DOT_STEP(15, accO)
    tau = accE + accO;
  }

  // ======== Phase 6: output ========
  if (r < 10) {
    out[gbi * 20 + c * 10 + r] = tau;
  }
}

extern "C" void kernel_launch(void* const* d_in, const int* in_sizes, int n_in,
                              void* d_out, int out_size, void* d_ws, size_t ws_size,
                              hipStream_t stream) {
  const float* x     = (const float*)d_in[0];
  const float* b     = (const float*)d_in[1];
  const float* W1    = (const float*)d_in[2];
  const float* b1    = (const float*)d_in[3];
  const float* W2    = (const float*)d_in[4];
  const float* b2    = (const float*)d_in[5];
  const float* P     = (const float*)d_in[6];
  const float* Pdot  = (const float*)d_in[7];
  const float* Pddot = (const float*)d_in[8];
  float* out = (float*)d_out;

  const int B = in_sizes[0] / 16;  // 512

  admm_kernel<<<B / 2, 64, 0, stream>>>(x, b, W1, b1, W2, b2, P, Pdot, Pddot, out);
}

// Round 6
// 68.344 us; speedup vs baseline: 1.6672x; 1.2866x over previous
//
#include <hip/hip_runtime.h>

#define NBODY 299  // prologue computes tau^(1); 299 body iters -> tau^(300)

// Broadcast within each 16-lane group (per 32-half, bit4 kept): init only.
#define BCAST(v, k) __int_as_float(__builtin_amdgcn_ds_swizzle(__float_as_int(v), (((k) << 5) | 0x10)))
// Swap the two 16-groups inside each 32-half: lane ^= 16  (x <-> y coord).
#define XOR16(v) __int_as_float(__builtin_amdgcn_ds_swizzle(__float_as_int(v), 0x401F))
// DPP row_ror:J within each 16-lane row: dst[r] = src[(r-J)&15]  (VALU pipe).
#define ROR(v, J) __int_as_float(__builtin_amdgcn_update_dpp(0, __float_as_int(v), 0x120 + (J), 0xF, 0xF, false))

// ---------------------------------------------------------------------------
// One wave (64 lanes) = 2 batch problems x 2 coords x 16 rows.
// lane = 16*q + r;  q = (problem<<1)|coord;  r = row (0..9 traj, 10..15 req).
// Recurrence (validated in round 5):
//   tau' = tau + W @ zeta
//     zeta_c (c<10)  = -4*tau_c + 2*cu_c - cu_prev_c + SumObs
//     zeta_c (c=10+e)= -tau_c + b_e
//   cu_k = sum_j u_kj,  u = max(1, rsqrt(wx^2+wy^2)) * w,  w = t_k - obs_j
// NEW: the 16x16 matvec W@zeta runs as a systolic DPP dot:
//   tau' = sum_j Wd[j] * row_ror_j(zeta),  Wd[j] = W[r][(r-j)&15]
// -> 15 independent v_mov_dpp + 16 fma per lane; zero LDS-pipe / readlane.
// ---------------------------------------------------------------------------
__global__ __launch_bounds__(64) void admm_kernel(
    const float* __restrict__ x, const float* __restrict__ b,
    const float* __restrict__ W1m, const float* __restrict__ b1,
    const float* __restrict__ W2m, const float* __restrict__ b2,
    const float* __restrict__ P, const float* __restrict__ Pdot,
    const float* __restrict__ Pddot, float* __restrict__ out) {
  __shared__ double Pd[10][11];
  __shared__ double Aq[6][11];
  __shared__ double M[11][22];
  __shared__ double U[16][11];
  __shared__ double colp[11];
  __shared__ float Wl[16][16];
  __shared__ float W1l[16];

  const int t = threadIdx.x;
  const int bid = blockIdx.x;

  // ======== Phase 1: per-block f64 precompute of W, rowsum(Gamma) ========
  for (int i = t; i < 110; i += 64) Pd[i / 11][i % 11] = (double)P[i];
  for (int i = t; i < 66; i += 64) {
    int e = i / 11, m = i % 11;
    const float* src = (e % 3 == 0) ? P : ((e % 3 == 1) ? Pdot : Pddot);
    Aq[e][m] = (double)src[(e < 3 ? 0 : 9) * 11 + m];
  }
  __syncthreads();

  for (int i = t; i < 121; i += 64) {
    int a = i / 11, c = i % 11;
    double acc = 0.0;
    for (int k = 0; k < 10; k++) acc += 10.0 * (double)Pddot[k * 11 + a] * (double)Pddot[k * 11 + c];
    for (int k = 0; k < 10; k++) acc += 4.8 * Pd[k][a] * Pd[k][c];
    for (int e = 0; e < 6; e++)  acc += 10.0 * Aq[e][a] * Aq[e][c];
    M[a][c] = acc;
    M[a][11 + c] = (a == c) ? 1.0 : 0.0;
  }
  __syncthreads();

  for (int p = 0; p < 11; p++) {
    double pv = M[p][p];
    __syncthreads();
    if (t < 22) M[p][t] *= (1.0 / pv);
    __syncthreads();
    if (t < 11) colp[t] = M[t][p];
    __syncthreads();
    for (int i = t; i < 242; i += 64) {
      int r = i / 22, c = i % 22;
      if (r != p) M[r][c] -= colp[r] * M[p][c];
    }
    __syncthreads();
  }

  for (int i = t; i < 176; i += 64) {
    int r = i / 11, m = i % 11;
    double acc = 0.0;
    for (int k = 0; k < 11; k++) acc += ((r < 10) ? Pd[r][k] : Aq[r - 10][k]) * M[k][11 + m];
    U[r][m] = acc;
  }
  __syncthreads();

  for (int i = t; i < 256; i += 64) {
    int r = i >> 4, c = i & 15;
    double acc = 0.0;
    if (c < 10) {
      for (int m = 0; m < 11; m++) acc += U[r][m] * Pd[c][m];
      acc *= 1.2;
    } else {
      for (int m = 0; m < 11; m++) acc += U[r][m] * Aq[c - 10][m];
      acc *= 10.0;
    }
    Wl[r][c] = (float)acc;
  }
  if (t < 16) {
    double acc = 0.0;
    for (int c = 0; c < 10; c++) {
      double d2 = 0.0;
      for (int m = 0; m < 11; m++) d2 += U[t][m] * Pd[c][m];
      acc += d2;
    }
    W1l[t] = (float)(1.2 * acc);
  }
  __syncthreads();

  // ======== Phase 2: MLP (b_pred[3], b_pred[9] for both problems) ========
  float w1r[16];
  #pragma unroll
  for (int k = 0; k < 16; k++) w1r[k] = W1m[t * 16 + k];

  float bp3_0, bp9_0, bp3_1, bp9_1;
  {
    const float* xr = x + (bid * 2 + 0) * 16;
    float a1 = b1[t];
    #pragma unroll
    for (int k = 0; k < 16; k++) a1 = fmaf(xr[k], w1r[k], a1);
    float hh = fmaxf(a1, 0.0f);
    float v3 = hh * W2m[3 * 64 + t];
    float v9 = hh * W2m[9 * 64 + t];
    #pragma unroll
    for (int dd = 32; dd >= 1; dd >>= 1) { v3 += __shfl_xor(v3, dd); v9 += __shfl_xor(v9, dd); }
    bp3_0 = v3 + b2[3];
    bp9_0 = v9 + b2[9];
  }
  {
    const float* xr = x + (bid * 2 + 1) * 16;
    float a1 = b1[t];
    #pragma unroll
    for (int k = 0; k < 16; k++) a1 = fmaf(xr[k], w1r[k], a1);
    float hh = fmaxf(a1, 0.0f);
    float v3 = hh * W2m[3 * 64 + t];
    float v9 = hh * W2m[9 * 64 + t];
    #pragma unroll
    for (int dd = 32; dd >= 1; dd >>= 1) { v3 += __shfl_xor(v3, dd); v9 += __shfl_xor(v9, dd); }
    bp3_1 = v3 + b2[3];
    bp9_1 = v9 + b2[9];
  }

  // ======== Phase 3: lane setup ========
  const int q = t >> 4, r = t & 15;
  const int pidx = q >> 1, c = q & 1;
  const int gbi = bid * 2 + pidx;

  // diagonal form of W for the systolic dot: Wd[j] = W[r][(r-j)&15]
  float Wd[16];
  #pragma unroll
  for (int j = 0; j < 16; j++) Wd[j] = Wl[r][(r - j) & 15];
  const float W1r = W1l[r];

  const bool isT = (r < 10);
  const float aC = isT ? -4.0f : -1.0f;
  const float m2 = isT ? 2.0f : 0.0f;
  const float mp = isT ? 1.0f : 0.0f;

  float bown = 0.0f;
  if (!isT) {
    int e = r - 10;
    float mlpv = (c == 0) ? (pidx ? bp3_1 : bp3_0) : (pidx ? bp9_1 : bp9_0);
    bown = (e == 3) ? mlpv : b[gbi * 12 + c * 6 + e];
  }
  const float dC = isT ? (c == 0 ? 130.79f : 69.2f) : bown;

  // obstacle constants (own coord / other coord)
  const float own0 = -10.0f;
  const float own1 = (c == 0) ? 100.79f : 100.0f;
  const float own2 = (c == 0) ? 30.0f : -30.8f;
  const float own3 = 10.0f;
  const float oth0 = -10.0f;
  const float oth1 = (c == 0) ? 100.0f : 100.79f;
  const float oth2 = (c == 0) ? -30.8f : 30.0f;
  const float oth3 = 10.0f;
  const float uz = (c == 0) ? 1.0f : 0.0f;  // atan2(0,0)=0 -> (ca,sa)=(1,0)

  // ======== Phase 4: init tau^(1), cu_prev^(0) ========
  float tau = (c == 0 ? 134.79f : 69.2f) * W1r;
  tau = fmaf(Wl[r][10], BCAST(bown, 10), tau);
  tau = fmaf(Wl[r][11], BCAST(bown, 11), tau);
  tau = fmaf(Wl[r][12], BCAST(bown, 12), tau);
  tau = fmaf(Wl[r][13], BCAST(bown, 13), tau);
  tau = fmaf(Wl[r][14], BCAST(bown, 14), tau);
  tau = fmaf(Wl[r][15], BCAST(bown, 15), tau);

  float cup = 4.0f * uz * mp;  // cu^(0): 4 for x-traj rows, else 0

  // ======== Phase 5: main loop ========
  #define PROJ_ACC(OWN, OTH)                                        \
    {                                                               \
      float wo = tau - (OWN), wt = to - (OTH);                      \
      float r2 = fmaf(wo, wo, wt * wt);                             \
      float sc = fmaxf(1.0f, __builtin_amdgcn_rsqf(r2));            \
      cu += (r2 > 0.0f) ? sc * wo : uz;                             \
    }

  for (int it = 0; it < NBODY; ++it) {
    float to = XOR16(tau);
    float cu;
    {
      float wo = tau - own0, wt = to - oth0;
      float r2 = fmaf(wo, wo, wt * wt);
      float sc = fmaxf(1.0f, __builtin_amdgcn_rsqf(r2));
      cu = (r2 > 0.0f) ? sc * wo : uz;
    }
    PROJ_ACC(own1, oth1)
    PROJ_ACC(own2, oth2)
    PROJ_ACC(own3, oth3)

    // zeta = aC*tau + m2*cu + dC - cu_prev
    float zeta = fmaf(aC, tau, fmaf(m2, cu, dC) - cup);
    cup = mp * cu;

    // systolic dot: tau' = tau + sum_j Wd[j] * ror_j(zeta)
    float a0 = fmaf(Wd[0], zeta, tau);
    float a1 = Wd[1] * ROR(zeta, 1);
    float a2 = Wd[2] * ROR(zeta, 2);
    float a3 = Wd[3] * ROR(zeta, 3);
    a0 = fmaf(Wd[4],  ROR(zeta, 4),  a0);
    a1 = fmaf(Wd[5],  ROR(zeta, 5),  a1);
    a2 = fmaf(Wd[6],  ROR(zeta, 6),  a2);
    a3 = fmaf(Wd[7],  ROR(zeta, 7),  a3);
    a0 = fmaf(Wd[8],  ROR(zeta, 8),  a0);
    a1 = fmaf(Wd[9],  ROR(zeta, 9),  a1);
    a2 = fmaf(Wd[10], ROR(zeta, 10), a2);
    a3 = fmaf(Wd[11], ROR(zeta, 11), a3);
    a0 = fmaf(Wd[12], ROR(zeta, 12), a0);
    a1 = fmaf(Wd[13], ROR(zeta, 13), a1);
    a2 = fmaf(Wd[14], ROR(zeta, 14), a2);
    a3 = fmaf(Wd[15], ROR(zeta, 15), a3);
    tau = (a0 + a1) + (a2 + a3);
  }

  // ======== Phase 6: output ========
  if (r < 10) {
    out[gbi * 20 + c * 10 + r] = tau;
  }
}

extern "C" void kernel_launch(void* const* d_in, const int* in_sizes, int n_in,
                              void* d_out, int out_size, void* d_ws, size_t ws_size,
                              hipStream_t stream) {
  const float* x     = (const float*)d_in[0];
  const float* b     = (const float*)d_in[1];
  const float* W1    = (const float*)d_in[2];
  const float* b1    = (const float*)d_in[3];
  const float* W2    = (const float*)d_in[4];
  const float* b2    = (const float*)d_in[5];
  const float* P     = (const float*)d_in[6];
  const float* Pdot  = (const float*)d_in[7];
  const float* Pddot = (const float*)d_in[8];
  float* out = (float*)d_out;

  const int B = in_sizes[0] / 16;  // 512

  admm_kernel<<<B / 2, 64, 0, stream>>>(x, b, W1, b1, W2, b2, P, Pdot, Pddot, out);
}